// Round 3
// baseline (563.775 us; speedup 1.0000x reference)
//
#include <hip/hip_runtime.h>

// N=64, CIN=COUT=64, T=256, V=25, S=3, REL=8
// ws layout (bytes):
//   [0, 8192)                : BN stats: sum at [o*16], sumsq at [1024 + o*16] (fp32)
//                              (overlaps xm region; memset AFTER k_small has consumed xm)
//   [0, 409600)              : xm[n][c][v] fp32 (102400 floats) -- k_xm -> k_small only
//   [409600, +17203200)      : R_bf16[s][n][o][u25][v28]  (v pad 25..27 = 0)
//                              (+ <=8B guarded read overrun, within proven ws bound)

#define WS_R_BYTE   409600

typedef __attribute__((ext_vector_type(8))) short bf16x8;
typedef __attribute__((ext_vector_type(4))) float f32x4;
typedef __attribute__((ext_vector_type(2))) unsigned int u32x2;
typedef __attribute__((ext_vector_type(4))) unsigned int u32x4;

static __device__ __forceinline__ unsigned short f2bf(float f) {
    unsigned int u = __float_as_uint(f);
    u += 0x7fff + ((u >> 16) & 1);          // RNE (finite values) -- harness-verified
    return (unsigned short)(u >> 16);
}
// pack two floats to bf16 pair (lo -> low 16 bits) via verified f2bf
static __device__ __forceinline__ unsigned pk2(float lo, float hi) {
    return (unsigned)f2bf(lo) | ((unsigned)f2bf(hi) << 16);
}

union BFRU { bf16x8 v; unsigned u[4]; u32x2 d[2]; };

// ---------------- K1: xm = mean over T ----------------
__global__ __launch_bounds__(256) void k_xm(const float* __restrict__ x,
                                            float* __restrict__ ws) {
    int idx = blockIdx.x * 256 + threadIdx.x;    // 102400 = 64*64*25
    int n = idx / 1600;
    int cv = idx % 1600;
    int c = cv / 25, v = cv % 25;
    const float* xp = x + (n * 64 + c) * 6400 + v;
    float s = 0.f;
    #pragma unroll 8
    for (int t = 0; t < 256; t++) s += xp[t * 25];
    ws[idx] = s * (1.f / 256.f);
}

// ---------------- K2: build R_bf16[s][n][o][u25][v28] ----------------
// one block per (s,n); 512 threads; 60000 B LDS
__global__ __launch_bounds__(512) void k_small(
    const float* __restrict__ ws, unsigned short* __restrict__ Rg,
    const float* __restrict__ A, const float* __restrict__ alphap,
    const float* __restrict__ w1, const float* __restrict__ b1,
    const float* __restrict__ w2, const float* __restrict__ b2,
    const float* __restrict__ w4, const float* __restrict__ b4,
    const float* __restrict__ pw1, const float* __restrict__ pb1,
    const float* __restrict__ pw2, const float* __restrict__ pb2,
    const float* __restrict__ dww, const float* __restrict__ pjw,
    const float* __restrict__ beta, const float* __restrict__ gamma) {
    __shared__ float sm[15000];
    const int tid = threadIdx.x;
    const int s = blockIdx.x >> 6;   // 0..2
    const int n = blockIdx.x & 63;   // 0..63
    const float alpha = alphap[0];
    const float gam = gamma[s], bet = beta[s];

    // 1. xm[n] -> sm[5000..6600)
    for (int i = tid; i < 1600; i += 512) sm[5000 + i] = ws[n * 1600 + i];
    __syncthreads();

    // 2. x1 (sm 6600..6800), x2 (sm 6800..7000)
    for (int i = tid; i < 400; i += 512) {
        int half = i / 200, j = i % 200;
        int r = j / 25, k = j % 25;
        const float* w = (half ? w2 : w1) + (s * 8 + r) * 64;
        float acc = (half ? b2 : b1)[s * 8 + r];
        for (int c = 0; c < 64; c++) acc += w[c] * sm[5000 + c * 25 + k];
        sm[6600 + i] = acc;
    }
    __syncthreads();

    // 3. q1[r,u,v] = tanh(x1[r,u]-x2[r,v]); A1 (7000..7200), B1 (7200..7400)
    for (int i = tid; i < 5400; i += 512) {
        if (i < 5000) {
            int r = i / 625, uv = i % 625, u = uv / 25, v = uv % 25;
            sm[i] = tanhf(sm[6600 + r * 25 + u] - sm[6800 + r * 25 + v]);
        } else {
            int i2 = i - 5000;  // 0..400
            int half = i2 / 200, j = i2 % 200;
            int r = j / 25, k = j % 25;
            float acc = 0.f;
            for (int p = 0; p < 8; p++)
                acc += pw1[(s * 8 + r) * 16 + half * 8 + p] * sm[6800 + p * 25 + k];
            sm[7000 + i2] = acc;
        }
    }
    __syncthreads();

    // 4. h[r,u,v] = relu(A1[r,u]+B1[r,v]+pb1[r]) -> [10000,15000)
    for (int i = tid; i < 5000; i += 512) {
        int r = i / 625, uv = i % 625, u = uv / 25, v = uv % 25;
        float t = sm[7000 + r * 25 + u] + sm[7200 + r * 25 + v] + pb1[s * 8 + r];
        sm[10000 + i] = t > 0.f ? t : 0.f;
    }
    __syncthreads();

    // 5. q_all = q1 + gamma*q2 -> [5000,10000)
    for (int i = tid; i < 5000; i += 512) {
        int r = i / 625, uv = i % 625;
        float q2 = pb2[s * 8 + r];
        for (int p = 0; p < 8; p++)
            q2 += pw2[(s * 8 + r) * 8 + p] * sm[10000 + p * 625 + uv];
        sm[5000 + i] = sm[i] + gam * q2;
    }
    __syncthreads();

    // 6. depthwise 3x3 conv on q1 -> tmp [10000,15000)
    for (int i = tid; i < 5000; i += 512) {
        int r = i / 625, uv = i % 625, u = uv / 25, v = uv % 25;
        float acc = 0.f;
        for (int di = 0; di < 3; di++) {
            int uu = u + di - 1;
            if (uu < 0 || uu > 24) continue;
            for (int dj = 0; dj < 3; dj++) {
                int vv = v + dj - 1;
                if (vv < 0 || vv > 24) continue;
                acc += sm[r * 625 + uu * 25 + vv] * dww[(s * 8 + r) * 9 + di * 3 + dj];
            }
        }
        sm[10000 + i] = acc;
    }
    __syncthreads();

    // 7. avgpool 3x3 (count_include_pad) + tanh -> overwrite q1 region
    for (int i = tid; i < 5000; i += 512) {
        int r = i / 625, uv = i % 625, u = uv / 25, v = uv % 25;
        float acc = 0.f;
        for (int di = 0; di < 3; di++) {
            int uu = u + di - 1;
            if (uu < 0 || uu > 24) continue;
            for (int dj = 0; dj < 3; dj++) {
                int vv = v + dj - 1;
                if (vv < 0 || vv > 24) continue;
                acc += sm[10000 + r * 625 + uu * 25 + vv];
            }
        }
        sm[i] = tanhf(acc * (1.f / 9.f));
    }
    __syncthreads();

    // 8. R[o][u][v] = alpha*(w4@q_all + b4) + A + beta*(pjw@tanhpool), bf16
    //    layout [o][u25][v28], v=25..27 zeroed (MFMA A-frag row order)
    unsigned short* Rb = Rg + (unsigned)((s * 64 + n)) * 44800u;
    for (int i = tid; i < 44800; i += 512) {
        int o = i / 700, uv = i % 700, uu = uv / 28, vv = uv % 28;
        unsigned short val = 0;
        if (vv < 25) {
            int quv = uu * 25 + vv;     // [u][v] index into q_all / pool
            float mn = b4[s * 64 + o], aux = 0.f;
            for (int r = 0; r < 8; r++) {
                mn  += w4[(s * 64 + o) * 8 + r] * sm[5000 + r * 625 + quv];
                aux += pjw[(s * 64 + o) * 8 + r] * sm[r * 625 + quv];
            }
            val = f2bf(mn * alpha + A[s * 625 + quv] + bet * aux);
        }
        Rb[i] = val;
    }
}

// ---------------- K3: main fused kernel: both stages on MFMA ----------------
// block = (n, t-tile of 16); 256 threads = 4 waves; wave w owns o-chunk [w*16, w*16+16)
// LDS: 65536 B union { xb[400][64] bf16 swizzled (51200 B) ; X3[64 o][16 t][32 v] bf16 }
// Per s: stage xb -> stage-1 MFMA (pack X3 to bf16 pairs on the fly, 52 VGPRs)
//   -> X3 to LDS -> stage-2 MFMA (A=R from global/L2, B=X3 from LDS). 4 barriers/s.
// All float->bf16 conversions via f2bf (harness-verified); no cvt_pk asm.
// BN batch stats fused into the epilogue (atomics into ws bnacc).
__global__ __launch_bounds__(256, 2) void k_main(
    const float* __restrict__ x, const float* __restrict__ w3,
    const float* __restrict__ b3, const unsigned short* __restrict__ Rg,
    float* __restrict__ out, float* __restrict__ bnacc) {
    __shared__ __align__(16) unsigned char smem[65536];
    unsigned short* xb  = (unsigned short*)smem;   // [tv 400][c 64], swizzled 16B chunks
    unsigned*       x3w = (unsigned*)smem;         // u32 view: [o 64][t 16][16 words]
    unsigned short* x3s = (unsigned short*)smem;   // ushort view: [o 64][t 16][v 32]

    const int tid  = threadIdx.x;
    const int n    = blockIdx.x >> 4;
    const int t0   = (blockIdx.x & 15) * 16;
    const int lane = tid & 63;
    const int w    = tid >> 6;          // wave id = o-chunk
    const int a    = lane & 15;
    const int q    = lane >> 4;         // quad
    const int og   = w * 16 + a;

    f32x4 yacc[16][2];                  // [o-in-chunk][u-tile]; accum across s
    #pragma unroll
    for (int k = 0; k < 16; k++) {
        yacc[k][0] = (f32x4){0.f, 0.f, 0.f, 0.f};
        yacc[k][1] = (f32x4){0.f, 0.f, 0.f, 0.f};
    }

    for (int s = 0; s < 3; s++) {
        // ---- stage x[n, :, t0:t0+16, :] -> xb bf16, swizzled (round-1 verified code;
        //      re-staged per s because X3 reuses the union region; x tile is L2/L3-hot) ----
        {
            const float* xbase = x + n * 409600 + t0 * 25;
            #pragma unroll 5
            for (int k = 0; k < 25; k++) {
                int i  = tid + k * 256;      // 0..6399
                int tv = i % 400;
                int cq = i / 400;            // c-quad 0..15
                const float* p = xbase + cq * 4 * 6400 + tv;
                ushort4 h;
                h.x = f2bf(p[0]); h.y = f2bf(p[6400]);
                h.z = f2bf(p[12800]); h.w = f2bf(p[19200]);
                int addr = tv * 64 + (((cq >> 1) ^ (tv & 7)) << 3) + ((cq & 1) << 2);
                *(ushort4*)&xb[addr] = h;
            }
        }
        __syncthreads();

        // ---- w3^T B-frags + bias (round-1 verified code) ----
        bf16x8 bfr[2];
        {
            const float* wp = w3 + (s * 64 + og) * 64;
            #pragma unroll
            for (int ks = 0; ks < 2; ks++)
                #pragma unroll
                for (int j = 0; j < 8; j++)
                    bfr[ks][j] = (short)f2bf(wp[ks * 32 + q * 8 + j]);
        }
        const float bias = b3[s * 64 + og];

        // ---- stage-1: X3[og][t=q*4+r][v] via MFMA over c; pack to bf16 pairs
        //      on the fly (x3pk[i][r] = (v=2i, v=2i+1) packed) ----
        unsigned x3pk[13][4];
        #pragma unroll
        for (int i = 0; i < 12; i++) {
            f32x4 ca, cb;
            {
                const int row = a * 25 + 2 * i;
                const int sw  = row & 7;
                bf16x8 a0 = *(const bf16x8*)&xb[row * 64 + ((q ^ sw) << 3)];
                bf16x8 a1 = *(const bf16x8*)&xb[row * 64 + (((4 + q) ^ sw) << 3)];
                f32x4 c0; c0[0] = bias; c0[1] = bias; c0[2] = bias; c0[3] = bias;
                c0 = __builtin_amdgcn_mfma_f32_16x16x32_bf16(a0, bfr[0], c0, 0, 0, 0);
                ca = __builtin_amdgcn_mfma_f32_16x16x32_bf16(a1, bfr[1], c0, 0, 0, 0);
            }
            {
                const int row = a * 25 + 2 * i + 1;
                const int sw  = row & 7;
                bf16x8 a0 = *(const bf16x8*)&xb[row * 64 + ((q ^ sw) << 3)];
                bf16x8 a1 = *(const bf16x8*)&xb[row * 64 + (((4 + q) ^ sw) << 3)];
                f32x4 c0; c0[0] = bias; c0[1] = bias; c0[2] = bias; c0[3] = bias;
                c0 = __builtin_amdgcn_mfma_f32_16x16x32_bf16(a0, bfr[0], c0, 0, 0, 0);
                cb = __builtin_amdgcn_mfma_f32_16x16x32_bf16(a1, bfr[1], c0, 0, 0, 0);
            }
            #pragma unroll
            for (int r = 0; r < 4; r++) x3pk[i][r] = pk2(ca[r], cb[r]);
        }
        {
            const int row = a * 25 + 24;
            const int sw  = row & 7;
            bf16x8 a0 = *(const bf16x8*)&xb[row * 64 + ((q ^ sw) << 3)];
            bf16x8 a1 = *(const bf16x8*)&xb[row * 64 + (((4 + q) ^ sw) << 3)];
            f32x4 c0; c0[0] = bias; c0[1] = bias; c0[2] = bias; c0[3] = bias;
            c0 = __builtin_amdgcn_mfma_f32_16x16x32_bf16(a0, bfr[0], c0, 0, 0, 0);
            c0 = __builtin_amdgcn_mfma_f32_16x16x32_bf16(a1, bfr[1], c0, 0, 0, 0);
            #pragma unroll
            for (int r = 0; r < 4; r++) x3pk[12][r] = pk2(c0[r], 0.f);
        }
        __syncthreads();    // all waves done reading xb

        // ---- write X3 to LDS [o][t][v32], v>=25 zeroed ----
        #pragma unroll
        for (int r = 0; r < 4; r++) {
            unsigned* dst = &x3w[og * 256 + (q * 4 + r) * 16];
            u32x4 w0, w1, w2, wd;
            w0[0] = x3pk[0][r];  w0[1] = x3pk[1][r];
            w0[2] = x3pk[2][r];  w0[3] = x3pk[3][r];
            w1[0] = x3pk[4][r];  w1[1] = x3pk[5][r];
            w1[2] = x3pk[6][r];  w1[3] = x3pk[7][r];
            w2[0] = x3pk[8][r];  w2[1] = x3pk[9][r];
            w2[2] = x3pk[10][r]; w2[3] = x3pk[11][r];
            wd[0] = x3pk[12][r]; wd[1] = 0u; wd[2] = 0u; wd[3] = 0u;
            *(u32x4*)(dst)      = w0;
            *(u32x4*)(dst + 4)  = w1;
            *(u32x4*)(dst + 8)  = w2;
            *(u32x4*)(dst + 12) = wd;
        }
        __syncthreads();    // X3 visible

        // ---- stage-2: y[u][t] += R[o][u][v] * X3[o][t][v] via MFMA ----
        const unsigned short* Rsn = Rg + (unsigned)((s * 64 + n)) * 44800u;
        #pragma unroll
        for (int k = 0; k < 16; k++) {
            const int o = w * 16 + k;
            const unsigned short* Ro = Rsn + o * 700;
            bf16x8 B = *(const bf16x8*)&x3s[o * 512 + a * 32 + q * 8];
            BFRU A0, A1;
            A0.d[0] = *(const u32x2*)(Ro + a * 28 + q * 8);
            A0.d[1] = *(const u32x2*)(Ro + a * 28 + q * 8 + 4);
            const int u1 = (a < 9) ? (16 + a) : 0;   // clamp: rows u>=25 discarded anyway
            A1.d[0] = *(const u32x2*)(Ro + u1 * 28 + q * 8);
            A1.d[1] = *(const u32x2*)(Ro + u1 * 28 + q * 8 + 4);
            yacc[k][0] = __builtin_amdgcn_mfma_f32_16x16x32_bf16(A0.v, B, yacc[k][0], 0, 0, 0);
            yacc[k][1] = __builtin_amdgcn_mfma_f32_16x16x32_bf16(A1.v, B, yacc[k][1], 0, 0, 0);
        }
        __syncthreads();    // reads done before next s overwrites union region
    }

    // ---- store y (scalar dwords, exact write-size) + fused BN stats ----
    // lane holds y[o = w*16+k][t = t0+a][u = tile*16 + q*4+r]
    float* outb = out + (unsigned)(n * 64) * 6400u + (t0 + a) * 25;
    #pragma unroll
    for (int k = 0; k < 16; k++) {
        const int o = w * 16 + k;
        float* op = outb + o * 6400;
        float s1 = 0.f, s2 = 0.f;
        #pragma unroll
        for (int r = 0; r < 4; r++) {
            float vv = yacc[k][0][r];
            op[q * 4 + r] = vv;
            s1 += vv; s2 += vv * vv;
        }
        #pragma unroll
        for (int r = 0; r < 4; r++) {
            int u = 16 + q * 4 + r;
            if (u < 25) {
                float vv = yacc[k][1][r];
                op[u] = vv;
                s1 += vv; s2 += vv * vv;
            }
        }
        #pragma unroll
        for (int off = 1; off < 64; off <<= 1) {
            s1 += __shfl_xor(s1, off);
            s2 += __shfl_xor(s2, off);
        }
        if (lane == 0) {
            atomicAdd(&bnacc[o * 16], s1);             // 64B-strided slots
            atomicAdd(&bnacc[1024 + o * 16], s2);
        }
    }
}

// ---------------- K5: normalize + residual + relu ----------------
// out_size = 26,214,400 floats = 6,553,600 float4 -> 25600 blocks x 256 threads
__global__ __launch_bounds__(256) void k_final(
    float* __restrict__ out, const float* __restrict__ x,
    const float* __restrict__ bnacc,
    const float* __restrict__ bnw, const float* __restrict__ bnb) {
    const int idx4 = blockIdx.x * 256 + threadIdx.x;   // < 6,553,600
    const int o = (idx4 / 1600) & 63;
    const float cnt = 1.f / 409600.f;
    float mean = bnacc[o * 16] * cnt;
    float var = bnacc[1024 + o * 16] * cnt - mean * mean;
    float inv = rsqrtf(var + 1e-5f);
    float sc = bnw[o] * inv;
    float sh = bnb[o] - mean * sc;
    float4 y = ((const float4*)out)[idx4];
    float4 xv = ((const float4*)x)[idx4];
    y.x = fmaxf(y.x * sc + sh + xv.x, 0.f);
    y.y = fmaxf(y.y * sc + sh + xv.y, 0.f);
    y.z = fmaxf(y.z * sc + sh + xv.z, 0.f);
    y.w = fmaxf(y.w * sc + sh + xv.w, 0.f);
    ((float4*)out)[idx4] = y;
}

extern "C" void kernel_launch(void* const* d_in, const int* in_sizes, int n_in,
                              void* d_out, int out_size, void* d_ws, size_t ws_size,
                              hipStream_t stream) {
    const float* x     = (const float*)d_in[0];
    const float* A     = (const float*)d_in[1];
    const float* alpha = (const float*)d_in[2];
    const float* w1    = (const float*)d_in[3];
    const float* b1    = (const float*)d_in[4];
    const float* w2    = (const float*)d_in[5];
    const float* b2    = (const float*)d_in[6];
    const float* w3    = (const float*)d_in[7];
    const float* b3    = (const float*)d_in[8];
    const float* w4    = (const float*)d_in[9];
    const float* b4    = (const float*)d_in[10];
    const float* pw1   = (const float*)d_in[11];
    const float* pb1   = (const float*)d_in[12];
    const float* pw2   = (const float*)d_in[13];
    const float* pb2   = (const float*)d_in[14];
    const float* dww   = (const float*)d_in[15];
    const float* pjw   = (const float*)d_in[16];
    const float* beta  = (const float*)d_in[17];
    const float* gamma = (const float*)d_in[18];
    const float* bnw   = (const float*)d_in[19];
    const float* bnb   = (const float*)d_in[20];
    float* out = (float*)d_out;
    float* ws  = (float*)d_ws;
    unsigned short* wsR = (unsigned short*)((char*)d_ws + WS_R_BYTE);
    float* wsBN = ws;   // overlaps xm region; memset after k_small has consumed xm

    k_xm<<<400, 256, 0, stream>>>(x, ws);
    k_small<<<192, 512, 0, stream>>>(ws, wsR, A, alpha, w1, b1, w2, b2,
                                     w4, b4, pw1, pb1, pw2, pb2, dww, pjw,
                                     beta, gamma);
    hipMemsetAsync(wsBN, 0, 8192, stream);
    k_main<<<1024, 256, 0, stream>>>(x, w3, b3, wsR, out, wsBN);
    k_final<<<25600, 256, 0, stream>>>(out, x, wsBN, bnw, bnb);
}